// Round 1
// baseline (334.049 us; speedup 1.0000x reference)
//
#include <hip/hip_runtime.h>
#include <cmath>
#include <vector>
#include <algorithm>

#define SEGS 16

struct FitParams {
    float blo[SEGS];   // segment lower bounds (exact f32)
    float c0[SEGS];    // x^2 coefficient (f32, matches np.polyfit cast)
    float c1[SEGS];    // x coefficient
    float c2[SEGS];    // const coefficient
};

// ---------------- host: replicate _fit_pieces() exactly ----------------
static void fit_pieces(FitParams& P) {
    const int NP = 10000;
    std::vector<double> xs(NP), ys(NP);
    const double delta = 10.0 / 9999.0;
    for (int i = 0; i < NP; ++i) xs[i] = -5.0 + (double)i * delta;
    xs[NP - 1] = 5.0;  // numpy linspace sets endpoint exactly
    const double s2 = sqrt(2.0);
    for (int i = 0; i < NP; ++i)
        ys[i] = 0.5 * xs[i] * (1.0 + erf(xs[i] / s2));

    double bounds[SEGS + 1];
    for (int j = 0; j <= SEGS; ++j) bounds[j] = -5.0 + (double)j * 0.625;

    for (int j = 0; j < SEGS; ++j) {
        const double lo = bounds[j], hi = bounds[j + 1];
        const double m = 0.5 * (lo + hi);  // shift for conditioning
        double S0 = 0, S1 = 0, S2 = 0, S3 = 0, S4 = 0;
        double b0 = 0, b1 = 0, b2 = 0;
        for (int i = 0; i < NP; ++i) {
            if (xs[i] >= lo && xs[i] <= hi) {
                const double t = xs[i] - m;
                const double t2 = t * t;
                S0 += 1.0; S1 += t; S2 += t2; S3 += t2 * t; S4 += t2 * t2;
                b0 += ys[i]; b1 += ys[i] * t; b2 += ys[i] * t2;
            }
        }
        // Solve symmetric 3x3 normal equations: p(t) = a0 + a1 t + a2 t^2
        double A[3][4] = {{S0, S1, S2, b0}, {S1, S2, S3, b1}, {S2, S3, S4, b2}};
        for (int col = 0; col < 3; ++col) {
            int piv = col;
            for (int r = col + 1; r < 3; ++r)
                if (fabs(A[r][col]) > fabs(A[piv][col])) piv = r;
            if (piv != col)
                for (int k = 0; k < 4; ++k) std::swap(A[col][k], A[piv][k]);
            for (int r = 0; r < 3; ++r) {
                if (r == col) continue;
                const double f = A[r][col] / A[col][col];
                for (int k = col; k < 4; ++k) A[r][k] -= f * A[col][k];
            }
        }
        const double a0 = A[0][3] / A[0][0];
        const double a1 = A[1][3] / A[1][1];
        const double a2 = A[2][3] / A[2][2];
        // expand back to p(x) = c0 x^2 + c1 x + c2 (highest power first, like polyfit)
        P.c0[j] = (float)a2;
        P.c1[j] = (float)(a1 - 2.0 * a2 * m);
        P.c2[j] = (float)((a2 * m - a1) * m + a0);
        P.blo[j] = (float)lo;  // exact in f32
    }
}

// ---------------- device ----------------
__global__ __launch_bounds__(256) void igelu_kernel(
        const float* __restrict__ x,
        const float* __restrict__ sf,
        float* __restrict__ out,
        int n4, int n, FitParams P)
{
    __shared__ float sc0[SEGS], sc1[SEGS], sc2[SEGS], slo[SEGS];
    const float s = sf[0];
    if (threadIdx.x < SEGS) {
        const int i = threadIdx.x;
        // match reference f32 semantics: lo_i = floor(BOUNDS_LO / s)
        slo[i] = floorf(P.blo[i] / s);
        const float twoN = 1048576.0f;  // 2^20
        // int_coeffs = floor(C * s^p * 2^N), p = 2,1,0
        sc0[i] = floorf((P.c0[i] * (s * s)) * twoN);
        sc1[i] = floorf((P.c1[i] * s) * twoN);
        sc2[i] = floorf(P.c2[i] * twoN);
    }
    __syncthreads();

    if (blockIdx.x == 0 && threadIdx.x == 0) {
        out[n] = sf[0] * 0x1p-20f;  // s / 2^20 (exact pow2 scale)
    }

    // segment thresholds into registers (wave-uniform values)
    float l[SEGS];
    #pragma unroll
    for (int i = 0; i < SEGS; ++i) l[i] = slo[i];

    const float4* __restrict__ x4 = (const float4*)x;
    float4* __restrict__ out4 = (float4*)out;
    const int stride = gridDim.x * blockDim.x;
    const int gid = blockIdx.x * blockDim.x + threadIdx.x;
    const float inv2N = 0x1p-20f;

    for (int t = gid; t < n4; t += stride) {
        const float4 v = x4[t];
        float in[4] = {v.x, v.y, v.z, v.w};
        float r[4];
        #pragma unroll
        for (int e = 0; e < 4; ++e) {
            const float xi = floorf(in[e] / s);  // IEEE f32 div, matches ref
            // idx = clip(searchsorted(lo_i, xi, 'right') - 1, 0, 15)
            //     = count(xi >= lo_i[1..15])   (clip folded in)
            int c = 0;
            #pragma unroll
            for (int i = 1; i < SEGS; ++i) c += (xi >= l[i]) ? 1 : 0;
            float rr = sc0[c];
            rr = rr * xi + sc1[c];
            rr = rr * xi + sc2[c];
            r[e] = rr * inv2N;  // r / 2^20, exact
        }
        out4[t] = make_float4(r[0], r[1], r[2], r[3]);
    }

    // scalar tail for n not divisible by 4 (robustness)
    for (int t = n4 * 4 + gid; t < n; t += stride) {
        const float xi = floorf(x[t] / s);
        int c = 0;
        #pragma unroll
        for (int i = 1; i < SEGS; ++i) c += (xi >= l[i]) ? 1 : 0;
        float rr = sc0[c];
        rr = rr * xi + sc1[c];
        rr = rr * xi + sc2[c];
        out[t] = rr * inv2N;
    }
}

// ---------------- launch ----------------
extern "C" void kernel_launch(void* const* d_in, const int* in_sizes, int n_in,
                              void* d_out, int out_size, void* d_ws, size_t ws_size,
                              hipStream_t stream) {
    FitParams P;
    fit_pieces(P);  // pure host compute, deterministic, same every call

    const float* x = (const float*)d_in[0];
    const float* sf = (const float*)d_in[1];
    float* out = (float*)d_out;
    const int n = in_sizes[0];
    const int n4 = n / 4;

    const int block = 256;
    const int grid = 2048;  // grid-stride; 256 CU * 8 blocks/CU
    igelu_kernel<<<grid, block, 0, stream>>>(x, sf, out, n4, n, P);
}